// Round 1
// baseline (11266.199 us; speedup 1.0000x reference)
//
#include <hip/hip_runtime.h>

#define BB 128
#define TT 1024
#define HH 256
#define EE 64
#define NC 10
#define GB 16
#define GH 8
#define BS 8    // batch rows per block
#define HS 32   // h cols per block per gate

// ws layout: h0buf [0,131072) bytes | cnt [131072,196608) | h1buf [196608,327680)

__global__ __launch_bounds__(256, 1) void lstm_persist(
    const int* __restrict__ x, const float* __restrict__ emb,
    const float* __restrict__ Wfx, const float* __restrict__ Wfh, const float* __restrict__ bfi,
    const float* __restrict__ Wix, const float* __restrict__ Wih, const float* __restrict__ bii,
    const float* __restrict__ Wgx, const float* __restrict__ Wgh, const float* __restrict__ bgi,
    const float* __restrict__ Wox, const float* __restrict__ Woh, const float* __restrict__ boi,
    const float* __restrict__ Wph, const float* __restrict__ Wpb,
    float* __restrict__ h0buf, float* __restrict__ h1buf,
    unsigned int* __restrict__ cnt, float* __restrict__ out)
{
  const int tid = threadIdx.x;
  const int bid = blockIdx.x;
  const int gb = bid & 15;   // peers share gb; bid%8 constant within group -> same XCD (perf only)
  const int gh = bid >> 4;   // 0..7
  const int b0 = gb * BS;
  const int j0 = gh * HS;
  const int w  = tid >> 6;        // wave id = gate (0=f,1=i,2=g,3=o)
  const int lane = tid & 63;
  const int jj = lane & 31;       // column within slice
  const int ks = lane >> 5;       // k-half selector

  __shared__ __align__(16) float hl[8 * 264];      // h rows, padded stride
  __shared__ float pre_sh[4 * 8 * 33];             // [gate][b][jj]
  __shared__ float xp_sh[3 * 4 * 32];              // [vocab][gate][jj]
  __shared__ int   xv[8];
  __shared__ float pj[8][10];

  // ---- per-block x-projection table (3 vocab x 4 gates x 32 cols), bias folded ----
  for (int idx = tid; idx < 384; idx += 256) {
    int v = idx >> 7;
    int g = (idx >> 5) & 3;
    int j = idx & 31;
    const float* Wx = (g == 0) ? Wfx : (g == 1) ? Wix : (g == 2) ? Wgx : Wox;
    const float* bs = (g == 0) ? bfi : (g == 1) ? bii : (g == 2) ? bgi : boi;
    float a = bs[j0 + j];
    const float* ev = emb + v * EE;
#pragma unroll 8
    for (int e = 0; e < EE; ++e) a = fmaf(ev[e], Wx[e * HH + j0 + j], a);
    xp_sh[(v * 4 + g) * 32 + j] = a;
  }

  // ---- recurrent weights into registers: lane holds W_gate[k][j0+jj] for its k-half ----
  const float* Wg = (w == 0) ? Wfh : (w == 1) ? Wih : (w == 2) ? Wgh : Woh;
  float wreg[128];
  {
    const float* wp = Wg + (ks * 128) * HH + j0 + jj;
#pragma unroll
    for (int kk = 0; kk < 128; ++kk) wreg[kk] = wp[kk * HH];
  }

  float creg = 0.f;               // cell state for (ub, ujj), fixed thread ownership
  const int ub  = tid >> 5;       // 0..7
  const int ujj = tid & 31;

  __syncthreads();                // xp_sh ready

  for (int t = 0; t < TT; ++t) {
    const int rb = t & 1;
    float* __restrict__ hr = rb ? h1buf : h0buf;   // read h(t-1)
    float* __restrict__ hw = rb ? h0buf : h1buf;   // write h(t)

    if (t > 0) {
      if (tid == 0) {
        while (__hip_atomic_load(&cnt[(gb << 10) + (t - 1)], __ATOMIC_ACQUIRE,
                                 __HIP_MEMORY_SCOPE_AGENT) < GH) { }
        __threadfence();          // agent acquire: invalidate before peer-data reads
      }
    }
    __syncthreads();              // S1

    // stage h rows (8 x 256 fp32) + x values for this t
    {
      const float4* src = (const float4*)(hr + b0 * HH);
#pragma unroll
      for (int r = 0; r < 2; ++r) {
        int idx = tid + r * 256;            // 0..511
        int bb = idx >> 6, c4 = idx & 63;
        *(float4*)&hl[bb * 264 + c4 * 4] = src[bb * 64 + c4];
      }
      if (tid < 8) xv[tid] = x[(b0 + tid) * TT + t];
    }
    __syncthreads();              // S2

    // k-loop: 8 batch-row accumulators over this lane's k-half (all static indices)
    float acc[8];
#pragma unroll
    for (int i = 0; i < 8; ++i) acc[i] = 0.f;
    const float* hbase = &hl[ks * 128];
#pragma unroll
    for (int k4 = 0; k4 < 32; ++k4) {
#pragma unroll
      for (int i = 0; i < 8; ++i) {
        float4 hv = *(const float4*)&hbase[i * 264 + k4 * 4];
        acc[i] = fmaf(hv.x, wreg[k4 * 4 + 0], acc[i]);
        acc[i] = fmaf(hv.y, wreg[k4 * 4 + 1], acc[i]);
        acc[i] = fmaf(hv.z, wreg[k4 * 4 + 2], acc[i]);
        acc[i] = fmaf(hv.w, wreg[k4 * 4 + 3], acc[i]);
      }
    }
#pragma unroll
    for (int i = 0; i < 8; ++i) acc[i] += __shfl_xor(acc[i], 32, 64);
    if (ks == 0) {
#pragma unroll
      for (int i = 0; i < 8; ++i) pre_sh[w * 264 + i * 33 + jj] = acc[i];
    }
    __syncthreads();              // S3

    // gate nonlinearities + c/h update (thread owns (ub,ujj))
    {
      int v = xv[ub];
      float pf = pre_sh[0 * 264 + ub * 33 + ujj] + xp_sh[(v * 4 + 0) * 32 + ujj];
      float pi = pre_sh[1 * 264 + ub * 33 + ujj] + xp_sh[(v * 4 + 1) * 32 + ujj];
      float pg = pre_sh[2 * 264 + ub * 33 + ujj] + xp_sh[(v * 4 + 2) * 32 + ujj];
      float po = pre_sh[3 * 264 + ub * 33 + ujj] + xp_sh[(v * 4 + 3) * 32 + ujj];
      float f = __fdividef(1.f, 1.f + __expf(-pf));
      float i = __fdividef(1.f, 1.f + __expf(-pi));
      float o = __fdividef(1.f, 1.f + __expf(-po));
      float gx = fminf(15.f, fmaxf(-15.f, pg));
      float eg = __expf(2.f * gx);
      float g = __fdividef(eg - 1.f, eg + 1.f);
      creg = f * creg + i * g;
      float cx = fminf(15.f, fmaxf(-15.f, creg));
      float ec = __expf(2.f * cx);
      float th = __fdividef(ec - 1.f, ec + 1.f);
      hw[(b0 + ub) * HH + j0 + ujj] = th * o;
    }
    __syncthreads();              // S4: vmcnt(0) drain of all threads' h stores
    if (tid == 0) {
      __threadfence();            // agent release: L2 writeback before flag
      __hip_atomic_fetch_add(&cnt[(gb << 10) + t], 1u, __ATOMIC_RELEASE,
                             __HIP_MEMORY_SCOPE_AGENT);
    }
  }

  // ---- final projection + log_softmax: one block per batch group ----
  if (gh != 0) return;
  if (tid == 0) {
    while (__hip_atomic_load(&cnt[(gb << 10) + (TT - 1)], __ATOMIC_ACQUIRE,
                             __HIP_MEMORY_SCOPE_AGENT) < GH) { }
    __threadfence();
  }
  __syncthreads();
  // t=1023 wrote into h0buf (rb=1 -> hw=h0buf)
  const float* hf = h0buf;
  if (tid < 80) {
    int b = tid / 10, cls = tid % 10;
    float a = Wpb[cls];
    const float* hrow = hf + (b0 + b) * HH;
    for (int k = 0; k < HH; ++k) a = fmaf(hrow[k], Wph[k * NC + cls], a);
    pj[b][cls] = a;
  }
  __syncthreads();
  if (tid < 8) {
    int b = tid;
    float m = pj[b][0];
#pragma unroll
    for (int c2 = 1; c2 < 10; ++c2) m = fmaxf(m, pj[b][c2]);
    float s = 0.f;
#pragma unroll
    for (int c2 = 0; c2 < 10; ++c2) s += __expf(pj[b][c2] - m);
    float ls = __logf(s);
#pragma unroll
    for (int c2 = 0; c2 < 10; ++c2) out[(b0 + b) * NC + c2] = pj[b][c2] - m - ls;
  }
}

extern "C" void kernel_launch(void* const* d_in, const int* in_sizes, int n_in,
                              void* d_out, int out_size, void* d_ws, size_t ws_size,
                              hipStream_t stream) {
  const int*   x   = (const int*)d_in[0];
  const float* emb = (const float*)d_in[1];
  const float* Wfx = (const float*)d_in[2];
  const float* Wfh = (const float*)d_in[3];
  const float* bf_ = (const float*)d_in[4];
  const float* Wix = (const float*)d_in[5];
  const float* Wih = (const float*)d_in[6];
  const float* bi_ = (const float*)d_in[7];
  const float* Wgx = (const float*)d_in[8];
  const float* Wgh = (const float*)d_in[9];
  const float* bg_ = (const float*)d_in[10];
  const float* Wox = (const float*)d_in[11];
  const float* Woh = (const float*)d_in[12];
  const float* bo_ = (const float*)d_in[13];
  const float* Wph = (const float*)d_in[14];
  const float* Wpb = (const float*)d_in[15];

  float* h0 = (float*)d_ws;
  unsigned int* c  = (unsigned int*)((char*)d_ws + 131072);
  float* h1 = (float*)((char*)d_ws + 196608);

  // zero h(t=-1) and the per-step arrival counters (replay-deterministic)
  hipMemsetAsync(d_ws, 0, 196608, stream);

  hipLaunchKernelGGL(lstm_persist, dim3(128), dim3(256), 0, stream,
      x, emb, Wfx, Wfh, bf_, Wix, Wih, bi_, Wgx, Wgh, bg_, Wox, Woh, bo_,
      Wph, Wpb, h0, h1, c, (float*)d_out);
}

// Round 2
// 5743.375 us; speedup vs baseline: 1.9616x; 1.9616x over previous
//
#include <hip/hip_runtime.h>

#define TT 1024
#define HH 256
#define EE 64
#define NC 10
#define SCA __HIP_MEMORY_SCOPE_AGENT

typedef float f32x2 __attribute__((ext_vector_type(2)));

// ws layout: h0 [0,131072) | cnt (16 groups x 128B pad) [131072,133120) | h1 [133120,264192)
// grid: 256 blocks = 16 batch-groups (gb) x 16 col-blocks (gc). Each block:
//   8 batch rows, 16 h-cols x 4 gates, full k=256.
// Sync: per-group monotonic counter; all cross-block data via sc0/sc1-scoped
// relaxed atomics (no buffer_wbl2/buffer_inv -- that was R1's 10us/step).

__global__ __launch_bounds__(256, 1) void lstm_persist(
    const int* __restrict__ x, const float* __restrict__ emb,
    const float* __restrict__ Wfx, const float* __restrict__ Wfh, const float* __restrict__ bfi,
    const float* __restrict__ Wix, const float* __restrict__ Wih, const float* __restrict__ bii,
    const float* __restrict__ Wgx, const float* __restrict__ Wgh, const float* __restrict__ bgi,
    const float* __restrict__ Wox, const float* __restrict__ Woh, const float* __restrict__ boi,
    const float* __restrict__ Wph, const float* __restrict__ Wpb,
    float* __restrict__ h0buf, float* __restrict__ h1buf,
    unsigned int* __restrict__ cnt, float* __restrict__ out)
{
  const int tid = threadIdx.x;
  const int bid = blockIdx.x;
  const int gb = bid & 15;    // peer blocks share gb; bid%8==gb%8 -> same XCD under round-robin (perf only)
  const int gc = bid >> 4;    // 0..15 col-block
  const int b0 = gb * 8;
  const int j0 = gc * 16;

  const int w    = tid >> 6;  // wave = gate (f,i,g,o)
  const int lane = tid & 63;
  const int ks   = lane >> 5; // k-half
  const int pos  = lane & 31;
  const int cp   = pos & 7;   // col-pair 0..7 -> cols 2cp,2cp+1
  const int rp   = pos >> 3;  // row-pair 0..3 -> rows 2rp,2rp+1

  __shared__ __align__(16) float hl[8 * 264];   // staged h rows
  __shared__ float pre_sh[4 * 8 * 17];          // [gate][row][col]
  __shared__ float xp_sh[3 * 4 * 16];           // [vocab][gate][col], bias folded
  __shared__ int   xv[8];
  __shared__ float pj[8][10];

  unsigned int* mycnt = cnt + gb * 32;          // 128B-padded counter

  // ---- x-projection table: 3 vocab x 4 gates x 16 cols ----
  for (int idx = tid; idx < 192; idx += 256) {
    int v = idx >> 6;
    int g = (idx >> 4) & 3;
    int j = idx & 15;
    const float* Wx = (g == 0) ? Wfx : (g == 1) ? Wix : (g == 2) ? Wgx : Wox;
    const float* bs = (g == 0) ? bfi : (g == 1) ? bii : (g == 2) ? bgi : boi;
    float a = bs[j0 + j];
    const float* ev = emb + v * EE;
#pragma unroll 8
    for (int e = 0; e < EE; ++e) a = fmaf(ev[e], Wx[e * HH + j0 + j], a);
    xp_sh[(v * 4 + g) * 16 + j] = a;
  }

  // ---- recurrent weights -> registers: float2 over the thread's 2 cols, its k-half ----
  const float* Wg = (w == 0) ? Wfh : (w == 1) ? Wih : (w == 2) ? Wgh : Woh;
  f32x2 wreg[128];
  {
    const float* wp = Wg + (ks * 128) * HH + j0 + 2 * cp;
#pragma unroll
    for (int kk = 0; kk < 128; ++kk) wreg[kk] = *(const f32x2*)(wp + kk * HH);
  }

  float creg = 0.f;                 // cell state, owned by tid<128 at (row,col)
  const int urow = tid >> 4;        // meaningful for tid<128
  const int ucol = tid & 15;

  __syncthreads();                  // xp_sh ready

  for (int t = 0; t < TT; ++t) {
    float* hr = (t & 1) ? h1buf : h0buf;   // read h(t-1)
    float* hw = (t & 1) ? h0buf : h1buf;   // write h(t)

    if (tid == 0 && t > 0) {
      const unsigned tgt = 16u * (unsigned)t;
      while (__hip_atomic_load(mycnt, __ATOMIC_RELAXED, SCA) < tgt) { }
    }
    __syncthreads();              // S1: peers' h(t-1) complete at coherence point

    // stage h(t-1): 8 rows x 256 via scoped loads (bypass stale L1/L2)
#pragma unroll
    for (int r8 = 0; r8 < 8; ++r8)
      hl[r8 * 264 + tid] = __hip_atomic_load(&hr[(b0 + r8) * HH + tid],
                                             __ATOMIC_RELAXED, SCA);
    if (tid < 8) xv[tid] = x[(b0 + tid) * TT + t];
    __syncthreads();              // S2

    // k-loop: 2 rows x 2 cols accumulators, this lane's k-half (static indices)
    float a00 = 0.f, a01 = 0.f, a10 = 0.f, a11 = 0.f;
    const float* hb0 = &hl[(2 * rp) * 264 + (ks << 7)];
    const float* hb1 = hb0 + 264;
#pragma unroll
    for (int k4 = 0; k4 < 32; ++k4) {
      float4 h0v = *(const float4*)(hb0 + k4 * 4);
      float4 h1v = *(const float4*)(hb1 + k4 * 4);
      f32x2 w0 = wreg[k4 * 4 + 0];
      f32x2 w1 = wreg[k4 * 4 + 1];
      f32x2 w2 = wreg[k4 * 4 + 2];
      f32x2 w3 = wreg[k4 * 4 + 3];
      a00 = fmaf(h0v.x, w0.x, a00); a01 = fmaf(h0v.x, w0.y, a01);
      a10 = fmaf(h1v.x, w0.x, a10); a11 = fmaf(h1v.x, w0.y, a11);
      a00 = fmaf(h0v.y, w1.x, a00); a01 = fmaf(h0v.y, w1.y, a01);
      a10 = fmaf(h1v.y, w1.x, a10); a11 = fmaf(h1v.y, w1.y, a11);
      a00 = fmaf(h0v.z, w2.x, a00); a01 = fmaf(h0v.z, w2.y, a01);
      a10 = fmaf(h1v.z, w2.x, a10); a11 = fmaf(h1v.z, w2.y, a11);
      a00 = fmaf(h0v.w, w3.x, a00); a01 = fmaf(h0v.w, w3.y, a01);
      a10 = fmaf(h1v.w, w3.x, a10); a11 = fmaf(h1v.w, w3.y, a11);
    }
    a00 += __shfl_xor(a00, 32, 64);
    a01 += __shfl_xor(a01, 32, 64);
    a10 += __shfl_xor(a10, 32, 64);
    a11 += __shfl_xor(a11, 32, 64);
    if (ks == 0) {
      float* p = &pre_sh[w * 136 + (2 * rp) * 17 + 2 * cp];
      p[0] = a00; p[1] = a01; p[17] = a10; p[18] = a11;
    }
    __syncthreads();              // S3

    if (tid < 128) {
      int v = xv[urow];
      float pf = pre_sh[0 * 136 + urow * 17 + ucol] + xp_sh[(v * 4 + 0) * 16 + ucol];
      float pi = pre_sh[1 * 136 + urow * 17 + ucol] + xp_sh[(v * 4 + 1) * 16 + ucol];
      float pg = pre_sh[2 * 136 + urow * 17 + ucol] + xp_sh[(v * 4 + 2) * 16 + ucol];
      float po = pre_sh[3 * 136 + urow * 17 + ucol] + xp_sh[(v * 4 + 3) * 16 + ucol];
      float f = __fdividef(1.f, 1.f + __expf(-pf));
      float i = __fdividef(1.f, 1.f + __expf(-pi));
      float o = __fdividef(1.f, 1.f + __expf(-po));
      float gx = fminf(15.f, fmaxf(-15.f, pg));
      float eg = __expf(2.f * gx);
      float g = __fdividef(eg - 1.f, eg + 1.f);
      creg = f * creg + i * g;
      float cx = fminf(15.f, fmaxf(-15.f, creg));
      float ec = __expf(2.f * cx);
      float th = __fdividef(ec - 1.f, ec + 1.f);
      __hip_atomic_store(&hw[(b0 + urow) * HH + j0 + ucol], th * o,
                         __ATOMIC_RELAXED, SCA);
    }
    __syncthreads();              // S4: barrier drain (vmcnt0) completes all h stores at L3
    if (tid == 0)
      __hip_atomic_fetch_add(mycnt, 1u, __ATOMIC_RELAXED, SCA);
  }

  // ---- final projection + log_softmax: gc==0 blocks ----
  if (gc != 0) return;
  if (tid == 0) {
    while (__hip_atomic_load(mycnt, __ATOMIC_RELAXED, SCA) < 16u * 1024u) { }
  }
  __syncthreads();
  // t=1023 (odd) wrote into h0buf
#pragma unroll
  for (int r8 = 0; r8 < 8; ++r8)
    hl[r8 * 264 + tid] = __hip_atomic_load(&h0buf[(b0 + r8) * HH + tid],
                                           __ATOMIC_RELAXED, SCA);
  __syncthreads();
  if (tid < 80) {
    int b = tid / 10, cls = tid % 10;
    float a = Wpb[cls];
    for (int k = 0; k < HH; ++k) a = fmaf(hl[b * 264 + k], Wph[k * NC + cls], a);
    pj[b][cls] = a;
  }
  __syncthreads();
  if (tid < 8) {
    int b = tid;
    float m = pj[b][0];
#pragma unroll
    for (int c2 = 1; c2 < 10; ++c2) m = fmaxf(m, pj[b][c2]);
    float s = 0.f;
#pragma unroll
    for (int c2 = 0; c2 < 10; ++c2) s += __expf(pj[b][c2] - m);
    float ls = __logf(s);
#pragma unroll
    for (int c2 = 0; c2 < 10; ++c2) out[(b0 + b) * NC + c2] = pj[b][c2] - m - ls;
  }
}

extern "C" void kernel_launch(void* const* d_in, const int* in_sizes, int n_in,
                              void* d_out, int out_size, void* d_ws, size_t ws_size,
                              hipStream_t stream) {
  const int*   x   = (const int*)d_in[0];
  const float* emb = (const float*)d_in[1];
  const float* Wfx = (const float*)d_in[2];
  const float* Wfh = (const float*)d_in[3];
  const float* bf_ = (const float*)d_in[4];
  const float* Wix = (const float*)d_in[5];
  const float* Wih = (const float*)d_in[6];
  const float* bi_ = (const float*)d_in[7];
  const float* Wgx = (const float*)d_in[8];
  const float* Wgh = (const float*)d_in[9];
  const float* bg_ = (const float*)d_in[10];
  const float* Wox = (const float*)d_in[11];
  const float* Woh = (const float*)d_in[12];
  const float* bo_ = (const float*)d_in[13];
  const float* Wph = (const float*)d_in[14];
  const float* Wpb = (const float*)d_in[15];

  float*        h0 = (float*)d_ws;
  unsigned int* c  = (unsigned int*)((char*)d_ws + 131072);
  float*        h1 = (float*)((char*)d_ws + 133120);

  // zero h(t=-1) + per-group counters (graph-replay deterministic)
  hipMemsetAsync(d_ws, 0, 133120, stream);

  hipLaunchKernelGGL(lstm_persist, dim3(256), dim3(256), 0, stream,
      x, emb, Wfx, Wfh, bf_, Wix, Wih, bi_, Wgx, Wgh, bg_, Wox, Woh, bo_,
      Wph, Wpb, h0, h1, c, (float*)d_out);
}